// Round 7
// baseline (242.602 us; speedup 1.0000x reference)
//
#include <hip/hip_runtime.h>
#include <math.h>

#define DIMS   256
#define KCODES 1024
#define NTOT   32768
#define TAU    4.0e-4f   // 3-term split distance-compare error <~6e-5; 6x margin
#define PAD    260

typedef __bf16 bf16x8 __attribute__((ext_vector_type(8)));
typedef float  f32x4  __attribute__((ext_vector_type(4)));

// ---- workspace layout (float indices; int views share) ----
#define WS_COMMIT   0          // float atomic
#define WS_FLAGCNT  1          // int atomic
#define WS_DECORR   2          // float atomic
#define WS_COLSUM   16         // float[256]
#define WS_COLSQ    272        // float[256]
// memset zero region: first 2112 bytes
#define WS_WSQ      1024       // float[1024]  (direct-stored)
#define WS_XSQ      2048       // float[32768] (direct-stored)
#define WS_FLAGS    34816      // int[32768]
#define WS_CAND1    67584      // float[16*32768]
#define WS_CAND2    591872     // float[16*32768]
#define WS_CANDI    1116160    // int[16*32768]
#define WS_WP       1640448    // bf16[524288] = 1 MB, fragment-ordered W

// ---- output layout (floats) ----
#define OUT_Q    0
#define OUT_IDX  8388608
#define OUT_SCAL 8421376

// Fragment layout (both Xp and Wp2), bf16 elems:
//   frag(bt, kt, wv, t, hl) base = ((((bt*8+kt)*2+wv)*4+t)*2+hl)*512
//   element (lane, e) at base + lane*8 + e  holds hi/lo bf16 of
//   src[row = bt*128+wv*64+t*16+(lane&15)][k = kt*32+(lane>>4)*8+e]

// ---------- fused prep ----------
// blocks [0,2048): pack X (16 rows each) | [2048,2112): pack W (+colstats) | [2112,2240): cov
__global__ __launch_bounds__(256) void prep_kernel(const float* __restrict__ X,
                                                   const float* __restrict__ W,
                                                   __bf16* __restrict__ Xp,
                                                   __bf16* __restrict__ Wp2,
                                                   float* ws) {
  int b = blockIdx.x;
  int tid = threadIdx.x;
  if (b < 2112) {
    __shared__ float xs[16 * PAD];
    bool isW = b >= 2048;
    const float* src = isW ? W : X;
    __bf16* dst = isW ? Wp2 : Xp;
    int r0 = (isW ? (b - 2048) : b) * 16;
    // coalesced stage: wave-instr = one full row (1 KB)
    #pragma unroll
    for (int it = 0; it < 4; it++) {
      int t = it * 256 + tid;
      int row = t >> 6, c4 = t & 63;
      *(float4*)&xs[row * PAD + c4 * 4] =
          *(const float4*)&src[(size_t)(r0 + row) * DIMS + c4 * 4];
    }
    __syncthreads();
    // row sum-of-squares (direct store, no atomics)
    {
      int row = tid >> 4, q = tid & 15;
      float sq = 0.f;
      #pragma unroll
      for (int e = 0; e < 16; e++) {
        float v = xs[row * PAD + q * 16 + e];
        sq = fmaf(v, v, sq);
      }
      sq += __shfl_xor(sq, 1);
      sq += __shfl_xor(sq, 2);
      sq += __shfl_xor(sq, 4);
      sq += __shfl_xor(sq, 8);
      if (q == 0) ws[(isW ? WS_WSQ : WS_XSQ) + r0 + row] = sq;
    }
    // colstats partials (W only)
    if (isW) {
      float s = 0.f, sq = 0.f;
      #pragma unroll
      for (int row = 0; row < 16; row++) {
        float v = xs[row * PAD + tid];
        s += v;
        sq = fmaf(v, v, sq);
      }
      atomicAdd(&ws[WS_COLSUM + tid], s);
      atomicAdd(&ws[WS_COLSQ + tid], sq);
    }
    // pack: wave w handles kt = w*2 + {0,1}; coalesced 1 KB frag writes
    int lane = tid & 63, wave = tid >> 6;
    int kq = lane >> 4, lc = lane & 15;
    int bt = r0 >> 7, g = (r0 >> 4) & 7, wv = g >> 2, t = g & 3;
    #pragma unroll
    for (int u = 0; u < 2; u++) {
      int kt = wave * 2 + u;
      bf16x8 hi, lo;
      #pragma unroll
      for (int e = 0; e < 8; e++) {
        float f = xs[lc * PAD + kt * 32 + kq * 8 + e];
        __bf16 h = (__bf16)f;
        hi[e] = h;
        lo[e] = (__bf16)(f - (float)h);
      }
      size_t base = ((((size_t)(bt * 8 + kt) * 2 + wv) * 4 + t) * 2) * 512;
      *(bf16x8*)&dst[base + lane * 8] = hi;
      *(bf16x8*)&dst[base + 512 + lane * 8] = lo;
    }
  } else {
    // cov: 128 blocks x 2 columns, self-contained means
    __shared__ float wi_s[2][KCODES];
    __shared__ float red2[256];
    __shared__ float mi_s[2];
    __shared__ float red[4];
    int i0 = (b - 2112) * 2;
    int rr = tid >> 1, cc = tid & 1;
    #pragma unroll
    for (int q = 0; q < 8; q++) {
      int row = q * 128 + rr;
      wi_s[cc][row] = W[(size_t)row * DIMS + i0 + cc];
    }
    __syncthreads();
    float pm = 0.f;
    #pragma unroll
    for (int q = 0; q < 8; q++) pm += wi_s[cc][rr * 8 + q];
    red2[tid] = pm;
    __syncthreads();
    if (tid < 2) {
      float s = 0.f;
      for (int k = tid; k < 256; k += 2) s += red2[k];
      mi_s[tid] = s * (1.0f / 1024.0f);
    }
    int j = tid;
    float a0 = 0.f, a1 = 0.f, sj = 0.f;
    for (int k = 0; k < KCODES; k += 4) {
      #pragma unroll
      for (int u = 0; u < 4; u++) {
        float wj = W[(size_t)(k + u) * DIMS + j];
        a0 = fmaf(wi_s[0][k + u], wj, a0);
        a1 = fmaf(wi_s[1][k + u], wj, a1);
        sj += wj;
      }
    }
    __syncthreads();  // mi_s ready
    const float inv = 1.0f / 1024.0f;
    float mj = sj * inv;
    float v = 0.f;
    float c0 = a0 * inv - mi_s[0] * mj;
    if (i0 != j) v = fmaf(c0, c0, v);
    float c1 = a1 * inv - mi_s[1] * mj;
    if (i0 + 1 != j) v = fmaf(c1, c1, v);
    #pragma unroll
    for (int m = 32; m >= 1; m >>= 1) v += __shfl_xor(v, m);
    if ((j & 63) == 0) red[j >> 6] = v;
    __syncthreads();
    if (j == 0) atomicAdd(&ws[WS_DECORR], (red[0] + red[1]) + (red[2] + red[3]));
  }
}

// ---------- pass1: barrier-free fragment GEMM, 4m x 2n wave tile, fenced reg dbuf ----------
// grid 4096: bm=(l&7)*32+((l>>3)&31) (0..255), bn=l>>8 (0..15); block tile 128m x 64n.
__global__ __launch_bounds__(256, 3) void pass1_kernel(const __bf16* __restrict__ Xp,
                                                       const __bf16* __restrict__ Wp2,
                                                       float* ws) {
  __shared__ float wsqs[64];
  __shared__ float d1L[256];
  __shared__ float d2L[256];
  __shared__ int   i1L[256];

  int tid = threadIdx.x;
  int lane = tid & 63, wave = tid >> 6;
  int wm = wave >> 1, wn = wave & 1;
  int quad = lane >> 4, col = lane & 15;
  int l = blockIdx.x;
  int bm = (l & 7) * 32 + ((l >> 3) & 31);
  int bn = l >> 8;
  int rowBase = bm * 128, cb = bn * 64;

  if (tid < 64) wsqs[tid] = ws[WS_WSQ + cb + tid];

  f32x4 acc[4][2];
  #pragma unroll
  for (int i = 0; i < 4; i++)
    #pragma unroll
    for (int j = 0; j < 2; j++) acc[i][j] = (f32x4){0.f, 0.f, 0.f, 0.f};

  // bf16x8-unit strides: kt=1024, frag t=128, hl=64
  const bf16x8* ab = (const bf16x8*)Xp + (size_t)bm * 8192 + wm * 512 + lane;
  const bf16x8* bb = (const bf16x8*)Wp2 + (size_t)(bn >> 1) * 8192 + (bn & 1) * 512 + wn * 256 + lane;

  bf16x8 Af[2][8], Bf[2][4];  // [buf][mt*2+hl] / [buf][nt*2+hl]
  #pragma unroll
  for (int mt = 0; mt < 4; mt++) {
    Af[0][mt * 2] = ab[mt * 128];
    Af[0][mt * 2 + 1] = ab[mt * 128 + 64];
  }
  #pragma unroll
  for (int nt = 0; nt < 2; nt++) {
    Bf[0][nt * 2] = bb[nt * 128];
    Bf[0][nt * 2 + 1] = bb[nt * 128 + 64];
  }
  #pragma unroll
  for (int kt = 0; kt < 8; kt++) {
    const int cur = kt & 1, nxt = cur ^ 1;
    if (kt < 7) {
      const bf16x8* an = ab + (kt + 1) * 1024;
      const bf16x8* bv = bb + (kt + 1) * 1024;
      #pragma unroll
      for (int mt = 0; mt < 4; mt++) {
        Af[nxt][mt * 2] = an[mt * 128];
        Af[nxt][mt * 2 + 1] = an[mt * 128 + 64];
      }
      #pragma unroll
      for (int nt = 0; nt < 2; nt++) {
        Bf[nxt][nt * 2] = bv[nt * 128];
        Bf[nxt][nt * 2 + 1] = bv[nt * 128 + 64];
      }
    }
    __builtin_amdgcn_sched_barrier(0);  // keep prefetch issue ahead of MFMA block
    #pragma unroll
    for (int nt = 0; nt < 2; nt++) {
      #pragma unroll
      for (int mt = 0; mt < 4; mt++) {
        acc[mt][nt] = __builtin_amdgcn_mfma_f32_16x16x32_bf16(Af[cur][mt * 2], Bf[cur][nt * 2], acc[mt][nt], 0, 0, 0);
        acc[mt][nt] = __builtin_amdgcn_mfma_f32_16x16x32_bf16(Af[cur][mt * 2], Bf[cur][nt * 2 + 1], acc[mt][nt], 0, 0, 0);
        acc[mt][nt] = __builtin_amdgcn_mfma_f32_16x16x32_bf16(Af[cur][mt * 2 + 1], Bf[cur][nt * 2], acc[mt][nt], 0, 0, 0);
      }
    }
    __builtin_amdgcn_sched_barrier(0);
  }
  __syncthreads();  // wsqs visibility

  // epilogue: per-row (best, 2nd, idx) over this block's 64 codes
  // C layout: row = quad*4 + reg, col = lane&15
  #pragma unroll
  for (int mt = 0; mt < 4; mt++) {
    #pragma unroll
    for (int r = 0; r < 4; r++) {
      float d1 = 3.0e38f, d2 = 3.0e38f;
      int i1 = 0;
      #pragma unroll
      for (int nt = 0; nt < 2; nt++) {
        int lc = wn * 32 + nt * 16 + col;
        float d = wsqs[lc] - 2.0f * acc[mt][nt][r];
        int g = cb + lc;
        if (d < d1) { d2 = d1; d1 = d; i1 = g; }
        else if (d < d2) d2 = d;
      }
      #pragma unroll
      for (int m = 1; m < 16; m <<= 1) {
        float od1 = __shfl_xor(d1, m);
        int oi1 = __shfl_xor(i1, m);
        float od2 = __shfl_xor(d2, m);
        if (od1 < d1 || (od1 == d1 && oi1 < i1)) {
          d2 = fminf(d1, fminf(d2, od2));
          d1 = od1; i1 = oi1;
        } else {
          d2 = fminf(od1, fminf(d2, od2));
        }
      }
      if (col == 0) {
        int lr = wm * 64 + mt * 16 + quad * 4 + r;
        d1L[lr * 2 + wn] = d1;
        d2L[lr * 2 + wn] = d2;
        i1L[lr * 2 + wn] = i1;
      }
    }
  }
  __syncthreads();
  if (tid < 128) {
    float a1 = d1L[tid * 2], a2 = d2L[tid * 2];
    int ai = i1L[tid * 2];
    float b1 = d1L[tid * 2 + 1], b2 = d2L[tid * 2 + 1];
    int bi = i1L[tid * 2 + 1];
    float m1, m2; int mi;
    if (b1 < a1 || (b1 == a1 && bi < ai)) { m1 = b1; mi = bi; m2 = fminf(a1, b2); }
    else { m1 = a1; mi = ai; m2 = fminf(b1, a2); }
    int o = bn * NTOT + rowBase + tid;
    ws[WS_CAND1 + o] = m1;
    ws[WS_CAND2 + o] = m2;
    ((int*)ws)[WS_CANDI + o] = mi;
  }
}

// ---------- pass2: merge 16 candidate sets; idx, commit, flags; parallel gather ----------
// grid 512, 64 rows per block
__global__ __launch_bounds__(256) void pass2_kernel(const float* __restrict__ W,
                                                    float* __restrict__ outQ,
                                                    float* __restrict__ outIdx, float* ws) {
  __shared__ int idx_s[64];
  int tid = threadIdx.x;
  int rowBase = blockIdx.x * 64;
  if (tid < 64) {
    int row = rowBase + tid;
    const float* c1 = ws + WS_CAND1;
    const float* c2 = ws + WS_CAND2;
    const int* ci = (const int*)ws + WS_CANDI;
    float m1 = 3.0e38f, m2 = 3.0e38f;
    int mi = 0;
    #pragma unroll
    for (int b = 0; b < 16; b++) {
      int o = b * NTOT + row;
      float b1 = c1[o], b2 = c2[o];
      int bi = ci[o];
      if (b1 < m1 || (b1 == m1 && bi < mi)) { m2 = fminf(m1, b2); m1 = b1; mi = bi; }
      else { m2 = fminf(m2, b1); }
    }
    outIdx[row] = (float)mi;
    idx_s[tid] = mi;
    int* wsI = (int*)ws;
    if (m2 - m1 < TAU) {
      int p = atomicAdd(&wsI[WS_FLAGCNT], 1);
      wsI[WS_FLAGS + p] = row;
    }
    float partial = ws[WS_XSQ + row] + m1;
    #pragma unroll
    for (int m = 32; m >= 1; m >>= 1) partial += __shfl_xor(partial, m);
    if (tid == 0) atomicAdd(&ws[WS_COMMIT], partial);
  }
  __syncthreads();
  int r = tid >> 4, l16 = tid & 15;
  #pragma unroll
  for (int it = 0; it < 4; it++) {
    int rl = it * 16 + r;
    int ix = idx_s[rl];
    const float4* wsrc = (const float4*)(W + (size_t)ix * DIMS);
    float4* qdst = (float4*)(outQ + (size_t)(rowBase + rl) * DIMS);
    #pragma unroll
    for (int c = 0; c < 4; c++) qdst[c * 16 + l16] = wsrc[c * 16 + l16];
  }
}

// ---------- f64 refinement (blocks 0..511) + fused scalar finalize (block 512) ----------
__global__ __launch_bounds__(256) void refine_kernel(const float* __restrict__ X,
                                                     const float* __restrict__ W,
                                                     float* __restrict__ outQ,
                                                     float* __restrict__ outIdx, float* ws,
                                                     const float* __restrict__ U,
                                                     float* __restrict__ out) {
  __shared__ float xs[DIMS];
  __shared__ double dm[256];
  __shared__ int im[256];
  __shared__ int chosen;
  int tid = threadIdx.x;
  if (blockIdx.x == 512) {
    // ---- finalize ----
    __shared__ float red[256];
    float s = 0.f;
    for (int e = tid; e < KCODES; e += 256) s += U[e] + 1e-5f;
    red[tid] = s;
    __syncthreads();
    for (int st = 128; st >= 1; st >>= 1) {
      if (tid < st) red[tid] += red[tid + st];
      __syncthreads();
    }
    float S = red[0];
    __syncthreads();
    float denom = fmaxf(S, 1e-5f * 1024.0f);
    float h = 0.f;
    for (int e = tid; e < KCODES; e += 256) {
      float p = (U[e] + 1e-5f) / denom;
      h += p * logf(p + 1e-5f);
    }
    red[tid] = h;
    __syncthreads();
    for (int st = 128; st >= 1; st >>= 1) {
      if (tid < st) red[tid] += red[tid + st];
      __syncthreads();
    }
    float H = -red[0] / 6.93147180559945f;  // ln(1024)
    __syncthreads();
    float m = ws[WS_COLSUM + tid] * (1.0f / 1024.0f);
    float var = ws[WS_COLSQ + tid] * (1.0f / 1024.0f) - m * m;
    float r = 0.05f - var;
    red[tid] = r > 0.f ? r : 0.f;
    __syncthreads();
    for (int st = 128; st >= 1; st >>= 1) {
      if (tid < st) red[tid] += red[tid + st];
      __syncthreads();
    }
    if (tid == 0) {
      float varloss = 1e-3f * (red[0] / 256.0f);
      float gap = H < 0.5f ? (0.5f - H) : (H > 0.9f ? (H - 0.9f) : 0.0f);
      float entloss = 0.1f * gap * gap;
      float commit = 0.25f * ws[WS_COMMIT] / 8388608.0f;
      float dec = 1e-3f * ws[WS_DECORR] / 65536.0f;
      float* sc = out + OUT_SCAL;
      sc[0] = commit + entloss + varloss + dec;
      sc[1] = commit;
      sc[2] = entloss;
      sc[3] = varloss;
      sc[4] = dec;
      sc[5] = H;
    }
    return;
  }
  const int* wsI = (const int*)ws;
  int cnt = wsI[WS_FLAGCNT];
  const int* list = wsI + WS_FLAGS;
  for (int f = blockIdx.x; f < cnt; f += 512) {
    int row = list[f];
    __syncthreads();
    if (tid < 64) ((float4*)xs)[tid] = ((const float4*)(X + (size_t)row * DIMS))[tid];
    __syncthreads();
    double bd = 1.0e300;
    int bi = 0;
    for (int jj = 0; jj < 4; jj++) {
      int c = tid + 256 * jj;
      double a0 = 0.0, a1 = 0.0, a2 = 0.0, a3 = 0.0;
      const float* wr = W + (size_t)c * DIMS;
      #pragma unroll 4
      for (int d4 = 0; d4 < 64; d4++) {
        float4 w = ((const float4*)wr)[d4];
        float4 x = ((const float4*)xs)[d4];
        double e0 = (double)x.x - (double)w.x;
        double e1 = (double)x.y - (double)w.y;
        double e2 = (double)x.z - (double)w.z;
        double e3 = (double)x.w - (double)w.w;
        a0 += e0 * e0; a1 += e1 * e1; a2 += e2 * e2; a3 += e3 * e3;
      }
      double s = (a0 + a1) + (a2 + a3);
      if (s < bd) { bd = s; bi = c; }
    }
    dm[tid] = bd; im[tid] = bi;
    __syncthreads();
    for (int st = 128; st >= 1; st >>= 1) {
      if (tid < st) {
        if (dm[tid + st] < dm[tid] || (dm[tid + st] == dm[tid] && im[tid + st] < im[tid])) {
          dm[tid] = dm[tid + st]; im[tid] = im[tid + st];
        }
      }
      __syncthreads();
    }
    if (tid == 0) { chosen = im[0]; outIdx[row] = (float)im[0]; }
    __syncthreads();
    int ix = chosen;
    if (tid < 64)
      ((float4*)(outQ + (size_t)row * DIMS))[tid] = ((const float4*)(W + (size_t)ix * DIMS))[tid];
  }
}

extern "C" void kernel_launch(void* const* d_in, const int* in_sizes, int n_in, void* d_out,
                              int out_size, void* d_ws, size_t ws_size, hipStream_t stream) {
  const float* X = (const float*)d_in[0];
  const float* W = (const float*)d_in[1];
  const float* U = (const float*)d_in[2];
  float* out = (float*)d_out;
  float* ws = (float*)d_ws;
  __bf16* Xp = (__bf16*)(out + OUT_Q);       // 33.55 MB, overwritten by pass2's gather
  __bf16* Wp2 = (__bf16*)(ws + WS_WP);       // 1 MB, fragment-ordered

  hipMemsetAsync(d_ws, 0, 2112, stream);
  prep_kernel<<<2240, 256, 0, stream>>>(X, W, Xp, Wp2, ws);
  pass1_kernel<<<4096, 256, 0, stream>>>(Xp, Wp2, ws);
  pass2_kernel<<<512, 256, 0, stream>>>(W, out + OUT_Q, out + OUT_IDX, ws);
  refine_kernel<<<513, 256, 0, stream>>>(X, W, out + OUT_Q, out + OUT_IDX, ws, U, out);
}